// Round 1
// baseline (1539.694 us; speedup 1.0000x reference)
//
#include <hip/hip_runtime.h>

#define IN_DIM 128
#define OUT_DIM 64
#define NEG_SLOPE 0.01f

// ---------------- zero scratch + output ----------------
__global__ void zero_kernel(int4* deg4, int ndeg4, float4* out4, int nout4) {
    int stride = gridDim.x * blockDim.x;
    int4 zi = {0, 0, 0, 0};
    float4 zf = make_float4(0.f, 0.f, 0.f, 0.f);
    for (int i = blockIdx.x * blockDim.x + threadIdx.x; i < ndeg4 + nout4; i += stride) {
        if (i < ndeg4) deg4[i] = zi;
        else out4[i - ndeg4] = zf;
    }
}

// ---------------- degree histogram ----------------
__global__ void degree_kernel(const int* __restrict__ es, const int* __restrict__ ed,
                              int* __restrict__ ds, int* __restrict__ dd, int E) {
    int e = blockIdx.x * blockDim.x + threadIdx.x;
    if (e < E) {
        atomicAdd(ds + es[e], 1);
        atomicAdd(dd + ed[e], 1);
    }
}

// ---------------- norms ----------------
__global__ void norm_kernel(const int* __restrict__ ds, const int* __restrict__ dd,
                            float* __restrict__ ns, float* __restrict__ nd, int n) {
    int i = blockIdx.x * blockDim.x + threadIdx.x;
    if (i < n) {
        ns[i] = rsqrtf((float)max(ds[i], 1));
        nd[i] = rsqrtf((float)max(dd[i], 1));
    }
}

// ---------------- x = (h * norm_src) @ W ----------------
// 64 rows per block, 256 threads, 4x4 micro-tile per thread.
// W staged fully (128x64 f32 = 32 KB); h staged in two 64-k halves (64x68 = 17.4 KB, pad 68 keeps
// the 4-distinct-address reads at 2-way bank aliasing which is free).
__global__ __launch_bounds__(256) void gemm_kernel(const float* __restrict__ h,
                                                   const float* __restrict__ W,
                                                   const float* __restrict__ ns,
                                                   float* __restrict__ x, int n) {
    __shared__ float Ws[IN_DIM * OUT_DIM];   // 32 KB
    __shared__ float hs[64][68];             // 17.4 KB
    int tid = threadIdx.x;
    int row0 = blockIdx.x * 64;

    {   // stage W (once)
        const float4* W4 = (const float4*)W;
        float4* Ws4 = (float4*)Ws;
        for (int i = tid; i < IN_DIM * OUT_DIM / 4; i += 256) Ws4[i] = W4[i];
    }

    int tc = tid & 15, tr = tid >> 4;
    int r0 = tr * 4, c0 = tc * 4;
    float acc[4][4];
#pragma unroll
    for (int i = 0; i < 4; i++)
#pragma unroll
        for (int j = 0; j < 4; j++) acc[i][j] = 0.f;

    for (int kh = 0; kh < 2; ++kh) {
        __syncthreads();
        // stage 64 rows x 64 k (one half), scaled by norm_src
        for (int i = tid; i < 1024; i += 256) {   // 1024 float4 = 64 rows * 16 f4
            int r = i >> 4, kq = i & 15;
            int row = row0 + r;
            float4 v = make_float4(0.f, 0.f, 0.f, 0.f);
            if (row < n) {
                v = ((const float4*)(h + (size_t)row * IN_DIM + kh * 64))[kq];
                float s = ns[row];
                v.x *= s; v.y *= s; v.z *= s; v.w *= s;
            }
            *(float4*)&hs[r][kq * 4] = v;
        }
        __syncthreads();
#pragma unroll
        for (int k = 0; k < 64; k += 4) {
            float4 a[4], w[4];
#pragma unroll
            for (int i = 0; i < 4; i++) a[i] = *(const float4*)&hs[r0 + i][k];
            int kg = (kh * 64 + k) * OUT_DIM + c0;
#pragma unroll
            for (int q = 0; q < 4; q++) w[q] = *(const float4*)&Ws[kg + q * OUT_DIM];
#pragma unroll
            for (int q = 0; q < 4; q++) {
#pragma unroll
                for (int i = 0; i < 4; i++) {
                    float aiq = (q == 0) ? a[i].x : (q == 1) ? a[i].y : (q == 2) ? a[i].z : a[i].w;
                    acc[i][0] += aiq * w[q].x;
                    acc[i][1] += aiq * w[q].y;
                    acc[i][2] += aiq * w[q].z;
                    acc[i][3] += aiq * w[q].w;
                }
            }
        }
    }
#pragma unroll
    for (int i = 0; i < 4; i++) {
        int row = row0 + r0 + i;
        if (row < n)
            *(float4*)&x[(size_t)row * OUT_DIM + c0] =
                make_float4(acc[i][0], acc[i][1], acc[i][2], acc[i][3]);
    }
}

// ---------------- edge scatter: out[dst] += x[src] ----------------
// 16 threads per edge, float4 each: coalesced 256B gather per edge row, 4 atomics/thread.
__global__ void scatter_kernel(const float* __restrict__ x, const int* __restrict__ es,
                               const int* __restrict__ ed, float* __restrict__ out, int E) {
    int gid = blockIdx.x * blockDim.x + threadIdx.x;
    int e = gid >> 4;
    if (e >= E) return;
    int p = gid & 15;
    int src = es[e], dst = ed[e];
    float4 v = ((const float4*)(x + (size_t)src * OUT_DIM))[p];
    float* o = out + (size_t)dst * OUT_DIM + p * 4;
    atomicAdd(o + 0, v.x);
    atomicAdd(o + 1, v.y);
    atomicAdd(o + 2, v.z);
    atomicAdd(o + 3, v.w);
}

// ---------------- finalize: out = leaky(out*norm_dst + b) ----------------
__global__ void finalize_kernel(float* __restrict__ out, const float* __restrict__ nd,
                                const float* __restrict__ b, int n) {
    int gid = blockIdx.x * blockDim.x + threadIdx.x;
    if (gid >= n * (OUT_DIM / 4)) return;
    int row = gid >> 4, p = gid & 15;
    float s = nd[row];
    float4 v = ((float4*)out)[gid];
    float4 bb = ((const float4*)b)[p];
    v.x = v.x * s + bb.x;
    v.y = v.y * s + bb.y;
    v.z = v.z * s + bb.z;
    v.w = v.w * s + bb.w;
    v.x = (v.x >= 0.f) ? v.x : NEG_SLOPE * v.x;
    v.y = (v.y >= 0.f) ? v.y : NEG_SLOPE * v.y;
    v.z = (v.z >= 0.f) ? v.z : NEG_SLOPE * v.z;
    v.w = (v.w >= 0.f) ? v.w : NEG_SLOPE * v.w;
    ((float4*)out)[gid] = v;
}

extern "C" void kernel_launch(void* const* d_in, const int* in_sizes, int n_in,
                              void* d_out, int out_size, void* d_ws, size_t ws_size,
                              hipStream_t stream) {
    const float* h = (const float*)d_in[0];
    const float* W = (const float*)d_in[1];
    const float* b = (const float*)d_in[2];
    const int* esrc = (const int*)d_in[3];
    const int* edst = (const int*)d_in[4];
    int n = in_sizes[0] / IN_DIM;   // 100000
    int E = in_sizes[3];            // 1600000
    float* out = (float*)d_out;

    // workspace layout (bytes): deg_src[n] | deg_dst[n] | norm_src[n] | norm_dst[n] | x[n*64]
    char* ws = (char*)d_ws;
    int* deg_s = (int*)ws;
    int* deg_d = (int*)(ws + (size_t)n * 4);
    float* norm_s = (float*)(ws + (size_t)n * 8);
    float* norm_d = (float*)(ws + (size_t)n * 12);
    float* x = (float*)(ws + (size_t)n * 16);

    int ndeg4 = (2 * n) / 4;          // 2n divisible by 4 (n=100000)
    int nout4 = n * (OUT_DIM / 4);
    zero_kernel<<<2048, 256, 0, stream>>>((int4*)deg_s, ndeg4, (float4*)out, nout4);
    degree_kernel<<<(E + 255) / 256, 256, 0, stream>>>(esrc, edst, deg_s, deg_d, E);
    norm_kernel<<<(n + 255) / 256, 256, 0, stream>>>(deg_s, deg_d, norm_s, norm_d, n);
    gemm_kernel<<<(n + 63) / 64, 256, 0, stream>>>(h, W, norm_s, x, n);
    scatter_kernel<<<(E * 16 + 255) / 256, 256, 0, stream>>>(x, esrc, edst, out, E);
    finalize_kernel<<<(n * 16 + 255) / 256, 256, 0, stream>>>(out, norm_d, b, n);
}

// Round 2
// 595.587 us; speedup vs baseline: 2.5852x; 2.5852x over previous
//
#include <hip/hip_runtime.h>

#define IN_DIM 128
#define OUT_DIM 64
#define NEG_SLOPE 0.01f

// ---------------- zero degree arrays ----------------
__global__ void zero_kernel(int4* p, int n4) {
    int i = blockIdx.x * blockDim.x + threadIdx.x;
    int4 z = {0, 0, 0, 0};
    if (i < n4) p[i] = z;
}

// ---------------- degree histograms ----------------
__global__ void degree_kernel(const int* __restrict__ es, const int* __restrict__ ed,
                              int* __restrict__ ds, int* __restrict__ dd, int E) {
    int e = blockIdx.x * blockDim.x + threadIdx.x;
    if (e < E) {
        atomicAdd(ds + es[e], 1);
        atomicAdd(dd + ed[e], 1);
    }
}

// ---------------- exclusive scan of in-degrees -> offsets, cursor ----------------
// Single block, 1024 threads, ~98 elements per thread. n = 100000 -> trivial.
__global__ __launch_bounds__(1024) void scan_kernel(const int* __restrict__ deg,
                                                    int* __restrict__ off,
                                                    int* __restrict__ cur, int n) {
    __shared__ int s[1024];
    int t = threadIdx.x;
    int chunk = (n + 1023) >> 10;
    int lo = t * chunk, hi = min(lo + chunk, n);
    int sum = 0;
    for (int i = lo; i < hi; i++) sum += deg[i];
    s[t] = sum;
    __syncthreads();
    for (int d = 1; d < 1024; d <<= 1) {   // inclusive Hillis-Steele
        int v = (t >= d) ? s[t - d] : 0;
        __syncthreads();
        s[t] += v;
        __syncthreads();
    }
    int base = s[t] - sum;                 // exclusive base for this chunk
    for (int i = lo; i < hi; i++) {
        off[i] = base;
        cur[i] = base;
        base += deg[i];
    }
    if (t == 1023) off[n] = s[1023];
}

// ---------------- bucket fill: csr[slot(dst)] = src ----------------
__global__ void fill_kernel(const int* __restrict__ es, const int* __restrict__ ed,
                            int* __restrict__ cur, int* __restrict__ csr, int E) {
    int e = blockIdx.x * blockDim.x + threadIdx.x;
    if (e < E) {
        int p = atomicAdd(cur + ed[e], 1);
        csr[p] = es[e];
    }
}

// ---------------- x = (h * rsqrt(out_deg)) @ W ----------------
// 64 rows per block, 256 threads, 4x4 micro-tile per thread.
__global__ __launch_bounds__(256) void gemm_kernel(const float* __restrict__ h,
                                                   const float* __restrict__ W,
                                                   const int* __restrict__ ds,
                                                   float* __restrict__ x, int n) {
    __shared__ float Ws[IN_DIM * OUT_DIM];   // 32 KB
    __shared__ float hs[64][68];             // 17.4 KB
    int tid = threadIdx.x;
    int row0 = blockIdx.x * 64;

    {   // stage W (once)
        const float4* W4 = (const float4*)W;
        float4* Ws4 = (float4*)Ws;
        for (int i = tid; i < IN_DIM * OUT_DIM / 4; i += 256) Ws4[i] = W4[i];
    }

    int tc = tid & 15, tr = tid >> 4;
    int r0 = tr * 4, c0 = tc * 4;
    float acc[4][4];
#pragma unroll
    for (int i = 0; i < 4; i++)
#pragma unroll
        for (int j = 0; j < 4; j++) acc[i][j] = 0.f;

    for (int kh = 0; kh < 2; ++kh) {
        __syncthreads();
        for (int i = tid; i < 1024; i += 256) {   // 64 rows * 16 float4
            int r = i >> 4, kq = i & 15;
            int row = row0 + r;
            float4 v = make_float4(0.f, 0.f, 0.f, 0.f);
            if (row < n) {
                v = ((const float4*)(h + (size_t)row * IN_DIM + kh * 64))[kq];
                float s = rsqrtf((float)max(ds[row], 1));
                v.x *= s; v.y *= s; v.z *= s; v.w *= s;
            }
            *(float4*)&hs[r][kq * 4] = v;
        }
        __syncthreads();
#pragma unroll
        for (int k = 0; k < 64; k += 4) {
            float4 a[4], w[4];
#pragma unroll
            for (int i = 0; i < 4; i++) a[i] = *(const float4*)&hs[r0 + i][k];
            int kg = (kh * 64 + k) * OUT_DIM + c0;
#pragma unroll
            for (int q = 0; q < 4; q++) w[q] = *(const float4*)&Ws[kg + q * OUT_DIM];
#pragma unroll
            for (int q = 0; q < 4; q++) {
#pragma unroll
                for (int i = 0; i < 4; i++) {
                    float aiq = (q == 0) ? a[i].x : (q == 1) ? a[i].y : (q == 2) ? a[i].z : a[i].w;
                    acc[i][0] += aiq * w[q].x;
                    acc[i][1] += aiq * w[q].y;
                    acc[i][2] += aiq * w[q].z;
                    acc[i][3] += aiq * w[q].w;
                }
            }
        }
    }
#pragma unroll
    for (int i = 0; i < 4; i++) {
        int row = row0 + r0 + i;
        if (row < n)
            *(float4*)&x[(size_t)row * OUT_DIM + c0] =
                make_float4(acc[i][0], acc[i][1], acc[i][2], acc[i][3]);
    }
}

// ---------------- gather-sum per dst node + fused epilogue ----------------
// One wave per node; lane = output column. Unroll-4 over the edge list for MLP.
__global__ __launch_bounds__(256) void gather_kernel(const float* __restrict__ x,
                                                     const int* __restrict__ csr,
                                                     const int* __restrict__ off,
                                                     const float* __restrict__ b,
                                                     float* __restrict__ out, int n) {
    int w = threadIdx.x >> 6;
    int lane = threadIdx.x & 63;
    int v = blockIdx.x * 4 + w;
    if (v >= n) return;
    int s0 = off[v], s1 = off[v + 1];
    float acc = 0.f;
    int j = s0;
    for (; j + 4 <= s1; j += 4) {
        int a0 = csr[j], a1 = csr[j + 1], a2 = csr[j + 2], a3 = csr[j + 3];
        float v0 = x[(size_t)a0 * OUT_DIM + lane];
        float v1 = x[(size_t)a1 * OUT_DIM + lane];
        float v2 = x[(size_t)a2 * OUT_DIM + lane];
        float v3 = x[(size_t)a3 * OUT_DIM + lane];
        acc += v0 + v1 + v2 + v3;
    }
    for (; j < s1; j++) acc += x[(size_t)csr[j] * OUT_DIM + lane];
    float nd = rsqrtf((float)max(s1 - s0, 1));
    float r = acc * nd + b[lane];
    out[(size_t)v * OUT_DIM + lane] = (r >= 0.f) ? r : NEG_SLOPE * r;
}

extern "C" void kernel_launch(void* const* d_in, const int* in_sizes, int n_in,
                              void* d_out, int out_size, void* d_ws, size_t ws_size,
                              hipStream_t stream) {
    const float* h = (const float*)d_in[0];
    const float* W = (const float*)d_in[1];
    const float* b = (const float*)d_in[2];
    const int* esrc = (const int*)d_in[3];
    const int* edst = (const int*)d_in[4];
    int n = in_sizes[0] / IN_DIM;   // 100000
    int E = in_sizes[3];            // 1600000
    float* out = (float*)d_out;

    // ws layout: deg_s[n] | deg_d[n] | off[n+4] | cur[n] | csr[E] | x[n*64]
    char* ws = (char*)d_ws;
    int* deg_s = (int*)ws;
    int* deg_d = (int*)(ws + (size_t)n * 4);
    int* off   = (int*)(ws + (size_t)n * 8);
    int* cur   = (int*)(ws + (size_t)n * 12 + 16);
    int* csr   = (int*)(ws + (size_t)n * 16 + 32);
    float* x   = (float*)(ws + (size_t)n * 16 + 32 + (size_t)E * 4);

    int ndeg4 = (2 * n + 3) / 4;
    zero_kernel<<<(ndeg4 + 255) / 256, 256, 0, stream>>>((int4*)deg_s, ndeg4);
    degree_kernel<<<(E + 255) / 256, 256, 0, stream>>>(esrc, edst, deg_s, deg_d, E);
    scan_kernel<<<1, 1024, 0, stream>>>(deg_d, off, cur, n);
    fill_kernel<<<(E + 255) / 256, 256, 0, stream>>>(esrc, edst, cur, csr, E);
    gemm_kernel<<<(n + 63) / 64, 256, 0, stream>>>(h, W, deg_s, x, n);
    gather_kernel<<<(n + 3) / 4, 256, 0, stream>>>(x, csr, off, b, out, n);
}

// Round 3
// 377.433 us; speedup vs baseline: 4.0794x; 1.5780x over previous
//
#include <hip/hip_runtime.h>

#define IN_DIM 128
#define OUT_DIM 64
#define NEG_SLOPE 0.01f
#define SCAN_CHUNK 1024   // elements per scan block

// ---------------- zero degree arrays ----------------
__global__ void zero_kernel(int4* p, int n4) {
    int i = blockIdx.x * blockDim.x + threadIdx.x;
    int4 z = {0, 0, 0, 0};
    if (i < n4) p[i] = z;
}

// ---------------- degree histograms ----------------
__global__ void degree_kernel(const int* __restrict__ es, const int* __restrict__ ed,
                              int* __restrict__ ds, int* __restrict__ dd, int E) {
    int e = blockIdx.x * blockDim.x + threadIdx.x;
    if (e < E) {
        atomicAdd(ds + es[e], 1);
        atomicAdd(dd + ed[e], 1);
    }
}

// ---------------- scan pass 1: per-block partial sums (1024 elems / block) ----------------
__global__ __launch_bounds__(256) void partial_kernel(const int* __restrict__ deg,
                                                      int* __restrict__ part, int n) {
    __shared__ int s[256];
    int t = threadIdx.x;
    int i0 = blockIdx.x * SCAN_CHUNK + t * 4;
    int tsum = 0;
    if (i0 < n) {   // n % 4 == 0 -> full int4 or nothing
        int4 d = *(const int4*)(deg + i0);
        tsum = d.x + d.y + d.z + d.w;
    }
    s[t] = tsum;
    __syncthreads();
    for (int d = 128; d > 0; d >>= 1) {
        if (t < d) s[t] += s[t + d];
        __syncthreads();
    }
    if (t == 0) part[blockIdx.x] = s[0];
}

// ---------------- scan pass 2: exclusive scan of partials (NB <= 128) ----------------
__global__ __launch_bounds__(128) void scanp_kernel(const int* __restrict__ part,
                                                    int* __restrict__ part_s, int nb) {
    __shared__ int s[128];
    int t = threadIdx.x;
    int v = (t < nb) ? part[t] : 0;
    s[t] = v;
    __syncthreads();
    for (int d = 1; d < 128; d <<= 1) {
        int u = (t >= d) ? s[t - d] : 0;
        __syncthreads();
        s[t] += u;
        __syncthreads();
    }
    if (t < nb) part_s[t] = s[t] - v;       // exclusive
    if (t == nb - 1) part_s[nb] = s[t];     // grand total
}

// ---------------- scan pass 3: per-element exclusive offsets ----------------
__global__ __launch_bounds__(256) void offsets_kernel(const int* __restrict__ deg,
                                                      const int* __restrict__ part_s,
                                                      int* __restrict__ off,
                                                      int* __restrict__ cur, int n, int nb) {
    __shared__ int s[256];
    int t = threadIdx.x;
    int i0 = blockIdx.x * SCAN_CHUNK + t * 4;
    int4 d = {0, 0, 0, 0};
    if (i0 < n) d = *(const int4*)(deg + i0);
    int tsum = d.x + d.y + d.z + d.w;
    s[t] = tsum;
    __syncthreads();
    for (int k = 1; k < 256; k <<= 1) {    // inclusive Hillis-Steele over thread sums
        int u = (t >= k) ? s[t - k] : 0;
        __syncthreads();
        s[t] += u;
        __syncthreads();
    }
    if (i0 < n) {
        int base = part_s[blockIdx.x] + s[t] - tsum;
        off[i0] = base;     cur[i0] = base;     base += d.x;
        off[i0 + 1] = base; cur[i0 + 1] = base; base += d.y;
        off[i0 + 2] = base; cur[i0 + 2] = base; base += d.z;
        off[i0 + 3] = base; cur[i0 + 3] = base;
    }
    if (blockIdx.x == 0 && t == 0) off[n] = part_s[nb];
}

// ---------------- bucket fill: csr[slot(dst)] = src ----------------
__global__ void fill_kernel(const int* __restrict__ es, const int* __restrict__ ed,
                            int* __restrict__ cur, int* __restrict__ csr, int E) {
    int e = blockIdx.x * blockDim.x + threadIdx.x;
    if (e < E) {
        int p = atomicAdd(cur + ed[e], 1);
        csr[p] = es[e];
    }
}

// ---------------- x = (h * rsqrt(out_deg)) @ W ----------------
__global__ __launch_bounds__(256) void gemm_kernel(const float* __restrict__ h,
                                                   const float* __restrict__ W,
                                                   const int* __restrict__ ds,
                                                   float* __restrict__ x, int n) {
    __shared__ float Ws[IN_DIM * OUT_DIM];   // 32 KB
    __shared__ float hs[64][68];             // 17.4 KB
    int tid = threadIdx.x;
    int row0 = blockIdx.x * 64;

    {
        const float4* W4 = (const float4*)W;
        float4* Ws4 = (float4*)Ws;
        for (int i = tid; i < IN_DIM * OUT_DIM / 4; i += 256) Ws4[i] = W4[i];
    }

    int tc = tid & 15, tr = tid >> 4;
    int r0 = tr * 4, c0 = tc * 4;
    float acc[4][4];
#pragma unroll
    for (int i = 0; i < 4; i++)
#pragma unroll
        for (int j = 0; j < 4; j++) acc[i][j] = 0.f;

    for (int kh = 0; kh < 2; ++kh) {
        __syncthreads();
        for (int i = tid; i < 1024; i += 256) {
            int r = i >> 4, kq = i & 15;
            int row = row0 + r;
            float4 v = make_float4(0.f, 0.f, 0.f, 0.f);
            if (row < n) {
                v = ((const float4*)(h + (size_t)row * IN_DIM + kh * 64))[kq];
                float s = rsqrtf((float)max(ds[row], 1));
                v.x *= s; v.y *= s; v.z *= s; v.w *= s;
            }
            *(float4*)&hs[r][kq * 4] = v;
        }
        __syncthreads();
#pragma unroll
        for (int k = 0; k < 64; k += 4) {
            float4 a[4], w[4];
#pragma unroll
            for (int i = 0; i < 4; i++) a[i] = *(const float4*)&hs[r0 + i][k];
            int kg = (kh * 64 + k) * OUT_DIM + c0;
#pragma unroll
            for (int q = 0; q < 4; q++) w[q] = *(const float4*)&Ws[kg + q * OUT_DIM];
#pragma unroll
            for (int q = 0; q < 4; q++) {
#pragma unroll
                for (int i = 0; i < 4; i++) {
                    float aiq = (q == 0) ? a[i].x : (q == 1) ? a[i].y : (q == 2) ? a[i].z : a[i].w;
                    acc[i][0] += aiq * w[q].x;
                    acc[i][1] += aiq * w[q].y;
                    acc[i][2] += aiq * w[q].z;
                    acc[i][3] += aiq * w[q].w;
                }
            }
        }
    }
#pragma unroll
    for (int i = 0; i < 4; i++) {
        int row = row0 + r0 + i;
        if (row < n)
            *(float4*)&x[(size_t)row * OUT_DIM + c0] =
                make_float4(acc[i][0], acc[i][1], acc[i][2], acc[i][3]);
    }
}

// ---------------- gather-sum per dst node + fused epilogue ----------------
// 16 lanes x float4 per node -> 4 nodes per wave, 16 nodes per 256-thread block.
__global__ __launch_bounds__(256) void gather_kernel(const float* __restrict__ x,
                                                     const int* __restrict__ csr,
                                                     const int* __restrict__ off,
                                                     const float* __restrict__ b,
                                                     float* __restrict__ out, int n) {
    int g = threadIdx.x >> 4;       // node slot in block
    int p = threadIdx.x & 15;       // float4 column
    int v = blockIdx.x * 16 + g;
    if (v >= n) return;
    int s0 = off[v], s1 = off[v + 1];
    float4 acc = make_float4(0.f, 0.f, 0.f, 0.f);
    int j = s0;
    for (; j + 4 <= s1; j += 4) {
        int a0 = csr[j], a1 = csr[j + 1], a2 = csr[j + 2], a3 = csr[j + 3];
        float4 v0 = ((const float4*)(x + (size_t)a0 * OUT_DIM))[p];
        float4 v1 = ((const float4*)(x + (size_t)a1 * OUT_DIM))[p];
        float4 v2 = ((const float4*)(x + (size_t)a2 * OUT_DIM))[p];
        float4 v3 = ((const float4*)(x + (size_t)a3 * OUT_DIM))[p];
        acc.x += v0.x + v1.x + v2.x + v3.x;
        acc.y += v0.y + v1.y + v2.y + v3.y;
        acc.z += v0.z + v1.z + v2.z + v3.z;
        acc.w += v0.w + v1.w + v2.w + v3.w;
    }
    for (; j < s1; j++) {
        float4 t = ((const float4*)(x + (size_t)csr[j] * OUT_DIM))[p];
        acc.x += t.x; acc.y += t.y; acc.z += t.z; acc.w += t.w;
    }
    float nd = rsqrtf((float)max(s1 - s0, 1));
    float4 bb = ((const float4*)b)[p];
    float4 r;
    r.x = acc.x * nd + bb.x;
    r.y = acc.y * nd + bb.y;
    r.z = acc.z * nd + bb.z;
    r.w = acc.w * nd + bb.w;
    r.x = (r.x >= 0.f) ? r.x : NEG_SLOPE * r.x;
    r.y = (r.y >= 0.f) ? r.y : NEG_SLOPE * r.y;
    r.z = (r.z >= 0.f) ? r.z : NEG_SLOPE * r.z;
    r.w = (r.w >= 0.f) ? r.w : NEG_SLOPE * r.w;
    ((float4*)(out + (size_t)v * OUT_DIM))[p] = r;
}

extern "C" void kernel_launch(void* const* d_in, const int* in_sizes, int n_in,
                              void* d_out, int out_size, void* d_ws, size_t ws_size,
                              hipStream_t stream) {
    const float* h = (const float*)d_in[0];
    const float* W = (const float*)d_in[1];
    const float* b = (const float*)d_in[2];
    const int* esrc = (const int*)d_in[3];
    const int* edst = (const int*)d_in[4];
    int n = in_sizes[0] / IN_DIM;   // 100000
    int E = in_sizes[3];            // 1600000
    float* out = (float*)d_out;

    // ws layout: deg_s[n] | deg_d[n] | off[n+4] | cur[n] | csr[E] | x[n*64]
    char* ws = (char*)d_ws;
    int* deg_s = (int*)ws;
    int* deg_d = (int*)(ws + (size_t)n * 4);
    int* off   = (int*)(ws + (size_t)n * 8);
    int* cur   = (int*)(ws + (size_t)n * 12 + 16);
    int* csr   = (int*)(ws + (size_t)n * 16 + 32);
    float* x   = (float*)(ws + (size_t)n * 16 + 32 + (size_t)E * 4);

    // scan partials aliased onto x's first bytes: consumed by offsets_kernel
    // BEFORE gemm_kernel writes x (stream-ordered) -> safe, deterministic.
    int nb = (n + SCAN_CHUNK - 1) / SCAN_CHUNK;   // 98
    int* part   = (int*)x;
    int* part_s = part + 256;                     // nb+1 <= 128 fits

    int ndeg4 = (2 * n + 3) / 4;
    zero_kernel<<<(ndeg4 + 255) / 256, 256, 0, stream>>>((int4*)deg_s, ndeg4);
    degree_kernel<<<(E + 255) / 256, 256, 0, stream>>>(esrc, edst, deg_s, deg_d, E);
    partial_kernel<<<nb, 256, 0, stream>>>(deg_d, part, n);
    scanp_kernel<<<1, 128, 0, stream>>>(part, part_s, nb);
    offsets_kernel<<<nb, 256, 0, stream>>>(deg_d, part_s, off, cur, n, nb);
    fill_kernel<<<(E + 255) / 256, 256, 0, stream>>>(esrc, edst, cur, csr, E);
    gemm_kernel<<<(n + 63) / 64, 256, 0, stream>>>(h, W, deg_s, x, n);
    gather_kernel<<<(n + 15) / 16, 256, 0, stream>>>(x, csr, off, b, out, n);
}

// Round 4
// 282.240 us; speedup vs baseline: 5.4553x; 1.3373x over previous
//
#include <hip/hip_runtime.h>

#define IN_DIM 128
#define OUT_DIM 64
#define NEG_SLOPE 0.01f
#define SCAN_CHUNK 1024   // nodes per scan block
#define ECHUNK 4096       // edges per binning block
// bucket = dst >> 8  (256 nodes per bucket)

// ---------------- zero degree arrays ----------------
__global__ void zero_kernel(int4* p, int n4) {
    int i = blockIdx.x * blockDim.x + threadIdx.x;
    int4 z = {0, 0, 0, 0};
    if (i < n4) p[i] = z;
}

// ---------------- degree histograms + per-chunk bucket histogram ----------------
__global__ __launch_bounds__(256) void degree_hist_kernel(
    const int* __restrict__ es, const int* __restrict__ ed,
    int* __restrict__ ds, int* __restrict__ dd,
    int* __restrict__ cntA, int E, int nbuck) {
    __shared__ int hist[512];
    int t = threadIdx.x;
    for (int i = t; i < nbuck; i += 256) hist[i] = 0;
    __syncthreads();
    int base = blockIdx.x * ECHUNK;
    for (int i = t; i < ECHUNK; i += 256) {
        int e = base + i;
        if (e < E) {
            int s = es[e], d = ed[e];
            atomicAdd(ds + s, 1);
            atomicAdd(dd + d, 1);
            atomicAdd(&hist[d >> 8], 1);
        }
    }
    __syncthreads();
    int row = blockIdx.x * nbuck;
    for (int i = t; i < nbuck; i += 256) cntA[row + i] = hist[i];
}

// ---------------- node-degree scan pass 1: per-block partial sums ----------------
__global__ __launch_bounds__(256) void partial_kernel(const int* __restrict__ deg,
                                                      int* __restrict__ part, int n) {
    __shared__ int s[256];
    int t = threadIdx.x;
    int i0 = blockIdx.x * SCAN_CHUNK + t * 4;
    int tsum = 0;
    if (i0 < n) {   // n % 4 == 0
        int4 d = *(const int4*)(deg + i0);
        tsum = d.x + d.y + d.z + d.w;
    }
    s[t] = tsum;
    __syncthreads();
    for (int d = 128; d > 0; d >>= 1) {
        if (t < d) s[t] += s[t + d];
        __syncthreads();
    }
    if (t == 0) part[blockIdx.x] = s[0];
}

// ---------------- node-degree scan pass 2: exclusive scan of partials ----------------
__global__ __launch_bounds__(128) void scanp_kernel(const int* __restrict__ part,
                                                    int* __restrict__ part_s, int nb) {
    __shared__ int s[128];
    int t = threadIdx.x;
    int v = (t < nb) ? part[t] : 0;
    s[t] = v;
    __syncthreads();
    for (int d = 1; d < 128; d <<= 1) {
        int u = (t >= d) ? s[t - d] : 0;
        __syncthreads();
        s[t] += u;
        __syncthreads();
    }
    if (t < nb) part_s[t] = s[t] - v;
    if (t == nb - 1) part_s[nb] = s[t];
}

// ---------------- node-degree scan pass 3: per-node exclusive offsets ----------------
__global__ __launch_bounds__(256) void offsets_kernel(const int* __restrict__ deg,
                                                      const int* __restrict__ part_s,
                                                      int* __restrict__ off, int n, int nb) {
    __shared__ int s[256];
    int t = threadIdx.x;
    int i0 = blockIdx.x * SCAN_CHUNK + t * 4;
    int4 d = {0, 0, 0, 0};
    if (i0 < n) d = *(const int4*)(deg + i0);
    int tsum = d.x + d.y + d.z + d.w;
    s[t] = tsum;
    __syncthreads();
    for (int k = 1; k < 256; k <<= 1) {
        int u = (t >= k) ? s[t - k] : 0;
        __syncthreads();
        s[t] += u;
        __syncthreads();
    }
    if (i0 < n) {
        int base = part_s[blockIdx.x] + s[t] - tsum;
        off[i0] = base;     base += d.x;
        off[i0 + 1] = base; base += d.y;
        off[i0 + 2] = base; base += d.z;
        off[i0 + 3] = base;
    }
    if (blockIdx.x == 0 && t == 0) off[n] = part_s[nb];
}

// ---------------- per-bucket exclusive scan over chunks: cntB[b][c] ----------------
__global__ __launch_bounds__(512) void cntscan_kernel(const int* __restrict__ cntA,
                                                      int* __restrict__ cntB,
                                                      int nchunk, int nbuck) {
    __shared__ int s[512];
    int t = threadIdx.x;
    int b = blockIdx.x;
    int v = (t < nchunk) ? cntA[t * nbuck + b] : 0;
    s[t] = v;
    __syncthreads();
    for (int d = 1; d < 512; d <<= 1) {
        int u = (t >= d) ? s[t - d] : 0;
        __syncthreads();
        s[t] += u;
        __syncthreads();
    }
    if (t < nchunk) cntB[b * nchunk + t] = s[t] - v;   // exclusive within bucket
}

// ---------------- bin edges by bucket: bp[slot] = src | (dst&255)<<24 ----------------
__global__ __launch_bounds__(256) void binpack_kernel(
    const int* __restrict__ es, const int* __restrict__ ed,
    const int* __restrict__ off, const int* __restrict__ cntB,
    int* __restrict__ bp, int E, int nchunk, int nbuck) {
    __shared__ int lcur[512];
    int t = threadIdx.x;
    int c = blockIdx.x;
    for (int i = t; i < nbuck; i += 256)
        lcur[i] = off[i << 8] + cntB[i * nchunk + c];
    __syncthreads();
    int base = c * ECHUNK;
    for (int i = t; i < ECHUNK; i += 256) {
        int e = base + i;
        if (e < E) {
            int s = es[e], d = ed[e];
            int pos = atomicAdd(&lcur[d >> 8], 1);
            bp[pos] = s | ((d & 255) << 24);   // src < 2^17, fits
        }
    }
}

// ---------------- within-bucket fill: csr[slot] = src (LDS cursors, dense writes) ----------------
__global__ __launch_bounds__(256) void bucketfill_kernel(
    const int* __restrict__ bp, const int* __restrict__ off,
    int* __restrict__ csr, int n, int nbuck) {
    __shared__ int cur[256];
    int t = threadIdx.x;
    int b = blockIdx.x;
    int node_lo = b << 8;
    int node_hi = min(n, node_lo + 256);
    if (node_lo + t < node_hi) cur[t] = off[node_lo + t];
    __syncthreads();
    int e_lo = off[node_lo], e_hi = off[node_hi];
    for (int i = e_lo + t; i < e_hi; i += 256) {
        int v = bp[i];
        int s = v & 0xFFFFFF;
        int d = (int)((unsigned)v >> 24);
        int slot = atomicAdd(&cur[d], 1);
        csr[slot] = s;
    }
}

// ---------------- x = (h * rsqrt(out_deg)) @ W ----------------
__global__ __launch_bounds__(256) void gemm_kernel(const float* __restrict__ h,
                                                   const float* __restrict__ W,
                                                   const int* __restrict__ ds,
                                                   float* __restrict__ x, int n) {
    __shared__ float Ws[IN_DIM * OUT_DIM];   // 32 KB
    __shared__ float hs[64][68];             // 17.4 KB
    int tid = threadIdx.x;
    int row0 = blockIdx.x * 64;

    {
        const float4* W4 = (const float4*)W;
        float4* Ws4 = (float4*)Ws;
        for (int i = tid; i < IN_DIM * OUT_DIM / 4; i += 256) Ws4[i] = W4[i];
    }

    int tc = tid & 15, tr = tid >> 4;
    int r0 = tr * 4, c0 = tc * 4;
    float acc[4][4];
#pragma unroll
    for (int i = 0; i < 4; i++)
#pragma unroll
        for (int j = 0; j < 4; j++) acc[i][j] = 0.f;

    for (int kh = 0; kh < 2; ++kh) {
        __syncthreads();
        for (int i = tid; i < 1024; i += 256) {
            int r = i >> 4, kq = i & 15;
            int row = row0 + r;
            float4 v = make_float4(0.f, 0.f, 0.f, 0.f);
            if (row < n) {
                v = ((const float4*)(h + (size_t)row * IN_DIM + kh * 64))[kq];
                float s = rsqrtf((float)max(ds[row], 1));
                v.x *= s; v.y *= s; v.z *= s; v.w *= s;
            }
            *(float4*)&hs[r][kq * 4] = v;
        }
        __syncthreads();
#pragma unroll
        for (int k = 0; k < 64; k += 4) {
            float4 a[4], w[4];
#pragma unroll
            for (int i = 0; i < 4; i++) a[i] = *(const float4*)&hs[r0 + i][k];
            int kg = (kh * 64 + k) * OUT_DIM + c0;
#pragma unroll
            for (int q = 0; q < 4; q++) w[q] = *(const float4*)&Ws[kg + q * OUT_DIM];
#pragma unroll
            for (int q = 0; q < 4; q++) {
#pragma unroll
                for (int i = 0; i < 4; i++) {
                    float aiq = (q == 0) ? a[i].x : (q == 1) ? a[i].y : (q == 2) ? a[i].z : a[i].w;
                    acc[i][0] += aiq * w[q].x;
                    acc[i][1] += aiq * w[q].y;
                    acc[i][2] += aiq * w[q].z;
                    acc[i][3] += aiq * w[q].w;
                }
            }
        }
    }
#pragma unroll
    for (int i = 0; i < 4; i++) {
        int row = row0 + r0 + i;
        if (row < n)
            *(float4*)&x[(size_t)row * OUT_DIM + c0] =
                make_float4(acc[i][0], acc[i][1], acc[i][2], acc[i][3]);
    }
}

// ---------------- gather-sum per dst node + fused epilogue ----------------
__global__ __launch_bounds__(256) void gather_kernel(const float* __restrict__ x,
                                                     const int* __restrict__ csr,
                                                     const int* __restrict__ off,
                                                     const float* __restrict__ b,
                                                     float* __restrict__ out, int n) {
    int g = threadIdx.x >> 4;
    int p = threadIdx.x & 15;
    int v = blockIdx.x * 16 + g;
    if (v >= n) return;
    int s0 = off[v], s1 = off[v + 1];
    float4 acc = make_float4(0.f, 0.f, 0.f, 0.f);
    int j = s0;
    for (; j + 4 <= s1; j += 4) {
        int a0 = csr[j], a1 = csr[j + 1], a2 = csr[j + 2], a3 = csr[j + 3];
        float4 v0 = ((const float4*)(x + (size_t)a0 * OUT_DIM))[p];
        float4 v1 = ((const float4*)(x + (size_t)a1 * OUT_DIM))[p];
        float4 v2 = ((const float4*)(x + (size_t)a2 * OUT_DIM))[p];
        float4 v3 = ((const float4*)(x + (size_t)a3 * OUT_DIM))[p];
        acc.x += v0.x + v1.x + v2.x + v3.x;
        acc.y += v0.y + v1.y + v2.y + v3.y;
        acc.z += v0.z + v1.z + v2.z + v3.z;
        acc.w += v0.w + v1.w + v2.w + v3.w;
    }
    for (; j < s1; j++) {
        float4 t = ((const float4*)(x + (size_t)csr[j] * OUT_DIM))[p];
        acc.x += t.x; acc.y += t.y; acc.z += t.z; acc.w += t.w;
    }
    float nd = rsqrtf((float)max(s1 - s0, 1));
    float4 bb = ((const float4*)b)[p];
    float4 r;
    r.x = acc.x * nd + bb.x;
    r.y = acc.y * nd + bb.y;
    r.z = acc.z * nd + bb.z;
    r.w = acc.w * nd + bb.w;
    r.x = (r.x >= 0.f) ? r.x : NEG_SLOPE * r.x;
    r.y = (r.y >= 0.f) ? r.y : NEG_SLOPE * r.y;
    r.z = (r.z >= 0.f) ? r.z : NEG_SLOPE * r.z;
    r.w = (r.w >= 0.f) ? r.w : NEG_SLOPE * r.w;
    ((float4*)(out + (size_t)v * OUT_DIM))[p] = r;
}

extern "C" void kernel_launch(void* const* d_in, const int* in_sizes, int n_in,
                              void* d_out, int out_size, void* d_ws, size_t ws_size,
                              hipStream_t stream) {
    const float* h = (const float*)d_in[0];
    const float* W = (const float*)d_in[1];
    const float* b = (const float*)d_in[2];
    const int* esrc = (const int*)d_in[3];
    const int* edst = (const int*)d_in[4];
    int n = in_sizes[0] / IN_DIM;   // 100000
    int E = in_sizes[3];            // 1600000
    float* out = (float*)d_out;

    // ws layout: deg_s[n] | deg_d[n] | off[n+4] | csr[E] | x[n*64]
    char* ws = (char*)d_ws;
    int* deg_s = (int*)ws;
    int* deg_d = (int*)(ws + (size_t)n * 4);
    int* off   = (int*)(ws + (size_t)n * 8);
    int* csr   = (int*)(ws + (size_t)n * 12 + 16);
    float* x   = (float*)(ws + (size_t)n * 12 + 16 + (size_t)E * 4);

    int nchunk = (E + ECHUNK - 1) / ECHUNK;        // 391
    int nbuck  = (n + 255) >> 8;                   // 391
    int nb     = (n + SCAN_CHUNK - 1) / SCAN_CHUNK; // 98

    // transient arrays aliased into x's 25.6 MB (all consumed before gemm writes x):
    char* xb = (char*)x;
    int* bp     = (int*)xb;                         // E ints = 6.4 MB
    int* cntA   = (int*)(xb + 6600000);             // nchunk*nbuck ints = 611 KB
    int* cntB   = (int*)(xb + 7300000);             // 611 KB
    int* part   = (int*)(xb + 8000000);             // nb ints
    int* part_s = (int*)(xb + 8001024);             // nb+1 ints

    int ndeg4 = (2 * n + 3) / 4;
    zero_kernel<<<(ndeg4 + 255) / 256, 256, 0, stream>>>((int4*)deg_s, ndeg4);
    degree_hist_kernel<<<nchunk, 256, 0, stream>>>(esrc, edst, deg_s, deg_d, cntA, E, nbuck);
    partial_kernel<<<nb, 256, 0, stream>>>(deg_d, part, n);
    scanp_kernel<<<1, 128, 0, stream>>>(part, part_s, nb);
    offsets_kernel<<<nb, 256, 0, stream>>>(deg_d, part_s, off, n, nb);
    cntscan_kernel<<<nbuck, 512, 0, stream>>>(cntA, cntB, nchunk, nbuck);
    binpack_kernel<<<nchunk, 256, 0, stream>>>(esrc, edst, off, cntB, bp, E, nchunk, nbuck);
    bucketfill_kernel<<<nbuck, 256, 0, stream>>>(bp, off, csr, n, nbuck);
    gemm_kernel<<<(n + 63) / 64, 256, 0, stream>>>(h, W, deg_s, x, n);
    gather_kernel<<<(n + 15) / 16, 256, 0, stream>>>(x, csr, off, b, out, n);
}

// Round 5
// 186.969 us; speedup vs baseline: 8.2350x; 1.5096x over previous
//
#include <hip/hip_runtime.h>

#define IN_DIM 128
#define OUT_DIM 64
#define NEG_SLOPE 0.01f
#define ECHUNK 4096       // edges per binning block
// bucket = node >> 8  (256 nodes per bucket)

// ---------------- per-chunk bucket histograms (dst and src), LDS only ----------------
__global__ __launch_bounds__(256) void hist_kernel(
    const int* __restrict__ es, const int* __restrict__ ed,
    int* __restrict__ cntA_d, int* __restrict__ cntA_s, int E, int nbuck) {
    __shared__ int hd[512];
    __shared__ int hs[512];
    int t = threadIdx.x;
    for (int i = t; i < nbuck; i += 256) { hd[i] = 0; hs[i] = 0; }
    __syncthreads();
    int base = blockIdx.x * ECHUNK;
    for (int i = t; i < ECHUNK; i += 256) {
        int e = base + i;
        if (e < E) {
            atomicAdd(&hd[ed[e] >> 8], 1);
            atomicAdd(&hs[es[e] >> 8], 1);
        }
    }
    __syncthreads();
    int row = blockIdx.x * nbuck;
    for (int i = t; i < nbuck; i += 256) {
        cntA_d[row + i] = hd[i];
        cntA_s[row + i] = hs[i];
    }
}

// ---------------- per-bucket exclusive scan over chunks + bucket totals ----------------
// grid = 2*nbuck: first nbuck blocks do dst, rest do src.
__global__ __launch_bounds__(512) void cntscan_kernel(
    const int* __restrict__ cntA_d, const int* __restrict__ cntA_s,
    int* __restrict__ cntB_d, int* __restrict__ cntB_s,
    int* __restrict__ tot_d, int* __restrict__ tot_s,
    int nchunk, int nbuck) {
    __shared__ int s[512];
    int t = threadIdx.x;
    int bid = blockIdx.x;
    const int* cntA = (bid < nbuck) ? cntA_d : cntA_s;
    int* cntB = (bid < nbuck) ? cntB_d : cntB_s;
    int* tot = (bid < nbuck) ? tot_d : tot_s;
    int b = (bid < nbuck) ? bid : bid - nbuck;
    int v = (t < nchunk) ? cntA[t * nbuck + b] : 0;
    s[t] = v;
    __syncthreads();
    for (int d = 1; d < 512; d <<= 1) {
        int u = (t >= d) ? s[t - d] : 0;
        __syncthreads();
        s[t] += u;
        __syncthreads();
    }
    if (t < nchunk) cntB[b * nchunk + t] = s[t] - v;
    if (t == 511) tot[b] = s[511];
}

// ---------------- exclusive scan over buckets -> bucket bases (dst and src) ----------------
__global__ __launch_bounds__(512) void base_kernel(
    const int* __restrict__ tot_d, const int* __restrict__ tot_s,
    int* __restrict__ base_d, int* __restrict__ base_s, int nbuck) {
    __shared__ int s[512];
    int t = threadIdx.x;
    for (int which = 0; which < 2; ++which) {
        const int* tot = which ? tot_s : tot_d;
        int* base = which ? base_s : base_d;
        int v = (t < nbuck) ? tot[t] : 0;
        s[t] = v;
        __syncthreads();
        for (int d = 1; d < 512; d <<= 1) {
            int u = (t >= d) ? s[t - d] : 0;
            __syncthreads();
            s[t] += u;
            __syncthreads();
        }
        if (t < nbuck) base[t] = s[t] - v;
        if (t == nbuck - 1) base[nbuck] = s[t];
        __syncthreads();
    }
}

// ---------------- bin edges by dst-bucket (packed) and src-bucket (byte) ----------------
__global__ __launch_bounds__(256) void binpack_kernel(
    const int* __restrict__ es, const int* __restrict__ ed,
    const int* __restrict__ base_d, const int* __restrict__ base_s,
    const int* __restrict__ cntB_d, const int* __restrict__ cntB_s,
    int* __restrict__ bp_dst, unsigned char* __restrict__ bp_src,
    int E, int nchunk, int nbuck) {
    __shared__ int ld[512];
    __shared__ int ls[512];
    int t = threadIdx.x;
    int c = blockIdx.x;
    for (int i = t; i < nbuck; i += 256) {
        ld[i] = base_d[i] + cntB_d[i * nchunk + c];
        ls[i] = base_s[i] + cntB_s[i * nchunk + c];
    }
    __syncthreads();
    int base = c * ECHUNK;
    for (int i = t; i < ECHUNK; i += 256) {
        int e = base + i;
        if (e < E) {
            int s = es[e], d = ed[e];
            int pd = atomicAdd(&ld[d >> 8], 1);
            bp_dst[pd] = s | ((d & 255) << 24);   // src < 2^17, fits in 24 bits
            int ps = atomicAdd(&ls[s >> 8], 1);
            bp_src[ps] = (unsigned char)(s & 255);
        }
    }
}

// ---------------- per-bucket src counts -> dense out-degree write ----------------
__global__ __launch_bounds__(256) void srccount_kernel(
    const unsigned char* __restrict__ bp_src, const int* __restrict__ base_s,
    int* __restrict__ ds, int n) {
    __shared__ int cnt[256];
    int t = threadIdx.x;
    int b = blockIdx.x;
    cnt[t] = 0;
    __syncthreads();
    int lo = base_s[b], hi = base_s[b + 1];
    for (int i = lo + t; i < hi; i += 256) atomicAdd(&cnt[bp_src[i]], 1);
    __syncthreads();
    int node = (b << 8) + t;
    if (node < n) ds[node] = cnt[t];
}

// ---------------- per-bucket dst counts -> off[] + csr fill (dense region) ----------------
__global__ __launch_bounds__(256) void dstfill_kernel(
    const int* __restrict__ bp_dst, const int* __restrict__ base_d,
    int* __restrict__ off, int* __restrict__ csr, int n, int E) {
    __shared__ int cnt[256];
    __shared__ int s[256];
    __shared__ int cur[256];
    int t = threadIdx.x;
    int b = blockIdx.x;
    cnt[t] = 0;
    __syncthreads();
    int lo = base_d[b], hi = base_d[b + 1];
    for (int i = lo + t; i < hi; i += 256)
        atomicAdd(&cnt[(int)((unsigned)bp_dst[i] >> 24)], 1);
    __syncthreads();
    int v = cnt[t];
    s[t] = v;
    __syncthreads();
    for (int d = 1; d < 256; d <<= 1) {
        int u = (t >= d) ? s[t - d] : 0;
        __syncthreads();
        s[t] += u;
        __syncthreads();
    }
    int obase = lo + s[t] - v;        // exclusive within bucket + bucket base
    int node = (b << 8) + t;
    if (node < n) off[node] = obase;
    cur[t] = obase;
    if (b == 0 && t == 0) off[n] = E;
    __syncthreads();
    for (int i = lo + t; i < hi; i += 256) {
        int w = bp_dst[i];
        int src = w & 0xFFFFFF;
        int d = (int)((unsigned)w >> 24);
        int slot = atomicAdd(&cur[d], 1);
        csr[slot] = src;
    }
}

// ---------------- x = (h * rsqrt(out_deg)) @ W ----------------
__global__ __launch_bounds__(256) void gemm_kernel(const float* __restrict__ h,
                                                   const float* __restrict__ W,
                                                   const int* __restrict__ ds,
                                                   float* __restrict__ x, int n) {
    __shared__ float Ws[IN_DIM * OUT_DIM];   // 32 KB
    __shared__ float hs[64][68];             // 17.4 KB
    int tid = threadIdx.x;
    int row0 = blockIdx.x * 64;

    {
        const float4* W4 = (const float4*)W;
        float4* Ws4 = (float4*)Ws;
        for (int i = tid; i < IN_DIM * OUT_DIM / 4; i += 256) Ws4[i] = W4[i];
    }

    int tc = tid & 15, tr = tid >> 4;
    int r0 = tr * 4, c0 = tc * 4;
    float acc[4][4];
#pragma unroll
    for (int i = 0; i < 4; i++)
#pragma unroll
        for (int j = 0; j < 4; j++) acc[i][j] = 0.f;

    for (int kh = 0; kh < 2; ++kh) {
        __syncthreads();
        for (int i = tid; i < 1024; i += 256) {
            int r = i >> 4, kq = i & 15;
            int row = row0 + r;
            float4 v = make_float4(0.f, 0.f, 0.f, 0.f);
            if (row < n) {
                v = ((const float4*)(h + (size_t)row * IN_DIM + kh * 64))[kq];
                float s = rsqrtf((float)max(ds[row], 1));
                v.x *= s; v.y *= s; v.z *= s; v.w *= s;
            }
            *(float4*)&hs[r][kq * 4] = v;
        }
        __syncthreads();
#pragma unroll
        for (int k = 0; k < 64; k += 4) {
            float4 a[4], w[4];
#pragma unroll
            for (int i = 0; i < 4; i++) a[i] = *(const float4*)&hs[r0 + i][k];
            int kg = (kh * 64 + k) * OUT_DIM + c0;
#pragma unroll
            for (int q = 0; q < 4; q++) w[q] = *(const float4*)&Ws[kg + q * OUT_DIM];
#pragma unroll
            for (int q = 0; q < 4; q++) {
#pragma unroll
                for (int i = 0; i < 4; i++) {
                    float aiq = (q == 0) ? a[i].x : (q == 1) ? a[i].y : (q == 2) ? a[i].z : a[i].w;
                    acc[i][0] += aiq * w[q].x;
                    acc[i][1] += aiq * w[q].y;
                    acc[i][2] += aiq * w[q].z;
                    acc[i][3] += aiq * w[q].w;
                }
            }
        }
    }
#pragma unroll
    for (int i = 0; i < 4; i++) {
        int row = row0 + r0 + i;
        if (row < n)
            *(float4*)&x[(size_t)row * OUT_DIM + c0] =
                make_float4(acc[i][0], acc[i][1], acc[i][2], acc[i][3]);
    }
}

// ---------------- gather-sum per dst node + fused epilogue ----------------
__global__ __launch_bounds__(256) void gather_kernel(const float* __restrict__ x,
                                                     const int* __restrict__ csr,
                                                     const int* __restrict__ off,
                                                     const float* __restrict__ b,
                                                     float* __restrict__ out, int n) {
    int g = threadIdx.x >> 4;
    int p = threadIdx.x & 15;
    int v = blockIdx.x * 16 + g;
    if (v >= n) return;
    int s0 = off[v], s1 = off[v + 1];
    float4 acc = make_float4(0.f, 0.f, 0.f, 0.f);
    int j = s0;
    for (; j + 4 <= s1; j += 4) {
        int a0 = csr[j], a1 = csr[j + 1], a2 = csr[j + 2], a3 = csr[j + 3];
        float4 v0 = ((const float4*)(x + (size_t)a0 * OUT_DIM))[p];
        float4 v1 = ((const float4*)(x + (size_t)a1 * OUT_DIM))[p];
        float4 v2 = ((const float4*)(x + (size_t)a2 * OUT_DIM))[p];
        float4 v3 = ((const float4*)(x + (size_t)a3 * OUT_DIM))[p];
        acc.x += v0.x + v1.x + v2.x + v3.x;
        acc.y += v0.y + v1.y + v2.y + v3.y;
        acc.z += v0.z + v1.z + v2.z + v3.z;
        acc.w += v0.w + v1.w + v2.w + v3.w;
    }
    for (; j < s1; j++) {
        float4 t = ((const float4*)(x + (size_t)csr[j] * OUT_DIM))[p];
        acc.x += t.x; acc.y += t.y; acc.z += t.z; acc.w += t.w;
    }
    float nd = rsqrtf((float)max(s1 - s0, 1));
    float4 bb = ((const float4*)b)[p];
    float4 r;
    r.x = acc.x * nd + bb.x;
    r.y = acc.y * nd + bb.y;
    r.z = acc.z * nd + bb.z;
    r.w = acc.w * nd + bb.w;
    r.x = (r.x >= 0.f) ? r.x : NEG_SLOPE * r.x;
    r.y = (r.y >= 0.f) ? r.y : NEG_SLOPE * r.y;
    r.z = (r.z >= 0.f) ? r.z : NEG_SLOPE * r.z;
    r.w = (r.w >= 0.f) ? r.w : NEG_SLOPE * r.w;
    ((float4*)(out + (size_t)v * OUT_DIM))[p] = r;
}

extern "C" void kernel_launch(void* const* d_in, const int* in_sizes, int n_in,
                              void* d_out, int out_size, void* d_ws, size_t ws_size,
                              hipStream_t stream) {
    const float* h = (const float*)d_in[0];
    const float* W = (const float*)d_in[1];
    const float* b = (const float*)d_in[2];
    const int* esrc = (const int*)d_in[3];
    const int* edst = (const int*)d_in[4];
    int n = in_sizes[0] / IN_DIM;   // 100000
    int E = in_sizes[3];            // 1600000
    float* out = (float*)d_out;

    // ws layout: ds[n] | off[n+4] | csr[E] | x[n*64]
    char* ws = (char*)d_ws;
    int* ds  = (int*)ws;
    int* off = (int*)(ws + (size_t)n * 4);
    int* csr = (int*)(ws + (size_t)n * 8 + 16);
    float* x = (float*)(ws + (size_t)n * 8 + 16 + (size_t)E * 4);

    int nchunk = (E + ECHUNK - 1) / ECHUNK;   // 391
    int nbuck  = (n + 255) >> 8;              // 391

    // transients aliased into x's 25.6 MB (all consumed before gemm writes x):
    char* xb = (char*)x;
    int* bp_dst = (int*)xb;                                   // 6.4 MB
    unsigned char* bp_src = (unsigned char*)(xb + 6600000);   // 1.6 MB
    int* cntA_d = (int*)(xb + 8400000);                       // 611 KB
    int* cntA_s = (int*)(xb + 9100000);
    int* cntB_d = (int*)(xb + 9800000);
    int* cntB_s = (int*)(xb + 10500000);
    int* tot_d  = (int*)(xb + 11200000);                      // nbuck+1
    int* tot_s  = (int*)(xb + 11210000);
    int* base_d = (int*)(xb + 11220000);                      // nbuck+1
    int* base_s = (int*)(xb + 11230000);

    hist_kernel<<<nchunk, 256, 0, stream>>>(esrc, edst, cntA_d, cntA_s, E, nbuck);
    cntscan_kernel<<<2 * nbuck, 512, 0, stream>>>(cntA_d, cntA_s, cntB_d, cntB_s,
                                                  tot_d, tot_s, nchunk, nbuck);
    base_kernel<<<1, 512, 0, stream>>>(tot_d, tot_s, base_d, base_s, nbuck);
    binpack_kernel<<<nchunk, 256, 0, stream>>>(esrc, edst, base_d, base_s,
                                               cntB_d, cntB_s, bp_dst, bp_src,
                                               E, nchunk, nbuck);
    srccount_kernel<<<nbuck, 256, 0, stream>>>(bp_src, base_s, ds, n);
    dstfill_kernel<<<nbuck, 256, 0, stream>>>(bp_dst, base_d, off, csr, n, E);
    gemm_kernel<<<(n + 63) / 64, 256, 0, stream>>>(h, W, ds, x, n);
    gather_kernel<<<(n + 15) / 16, 256, 0, stream>>>(x, csr, off, b, out, n);
}

// Round 6
// 151.121 us; speedup vs baseline: 10.1885x; 1.2372x over previous
//
#include <hip/hip_runtime.h>

#define IN_DIM 128
#define OUT_DIM 64
#define NEG_SLOPE 0.01f
#define ECHUNK 4096       // edges per binning block
// bucket = node >> 8  (256 nodes per bucket)

// bf16 helpers: memory layout = 16-bit, value = bits<<16
__device__ inline float bf_lo(unsigned u) { union { unsigned i; float f; } c; c.i = u << 16; return c.f; }
__device__ inline float bf_hi(unsigned u) { union { unsigned i; float f; } c; c.i = u & 0xFFFF0000u; return c.f; }
__device__ inline unsigned short f2b(float f) {
    union { float f; unsigned i; } c; c.f = f;
    unsigned u = c.i + 0x7FFFu + ((c.i >> 16) & 1u);   // round-to-nearest-even
    return (unsigned short)(u >> 16);
}

// ---------------- per-chunk bucket histograms (dst and src), LDS only ----------------
__global__ __launch_bounds__(256) void hist_kernel(
    const int* __restrict__ es, const int* __restrict__ ed,
    int* __restrict__ cntA_d, int* __restrict__ cntA_s, int E, int nbuck) {
    __shared__ int hd[512];
    __shared__ int hs[512];
    int t = threadIdx.x;
    for (int i = t; i < nbuck; i += 256) { hd[i] = 0; hs[i] = 0; }
    __syncthreads();
    int base = blockIdx.x * ECHUNK;
    for (int i = t * 4; i < ECHUNK; i += 1024) {   // int4 loads; E%4==0
        int e = base + i;
        if (e < E) {
            int4 d4 = *(const int4*)(ed + e);
            int4 s4 = *(const int4*)(es + e);
            atomicAdd(&hd[d4.x >> 8], 1); atomicAdd(&hd[d4.y >> 8], 1);
            atomicAdd(&hd[d4.z >> 8], 1); atomicAdd(&hd[d4.w >> 8], 1);
            atomicAdd(&hs[s4.x >> 8], 1); atomicAdd(&hs[s4.y >> 8], 1);
            atomicAdd(&hs[s4.z >> 8], 1); atomicAdd(&hs[s4.w >> 8], 1);
        }
    }
    __syncthreads();
    int row = blockIdx.x * nbuck;
    for (int i = t; i < nbuck; i += 256) {
        cntA_d[row + i] = hd[i];
        cntA_s[row + i] = hs[i];
    }
}

// ---------------- per-bucket exclusive scan over chunks + bucket totals ----------------
__global__ __launch_bounds__(512) void cntscan_kernel(
    const int* __restrict__ cntA_d, const int* __restrict__ cntA_s,
    int* __restrict__ cntB_d, int* __restrict__ cntB_s,
    int* __restrict__ tot_d, int* __restrict__ tot_s,
    int nchunk, int nbuck) {
    __shared__ int s[512];
    int t = threadIdx.x;
    int bid = blockIdx.x;
    const int* cntA = (bid < nbuck) ? cntA_d : cntA_s;
    int* cntB = (bid < nbuck) ? cntB_d : cntB_s;
    int* tot = (bid < nbuck) ? tot_d : tot_s;
    int b = (bid < nbuck) ? bid : bid - nbuck;
    int v = (t < nchunk) ? cntA[t * nbuck + b] : 0;
    s[t] = v;
    __syncthreads();
    for (int d = 1; d < 512; d <<= 1) {
        int u = (t >= d) ? s[t - d] : 0;
        __syncthreads();
        s[t] += u;
        __syncthreads();
    }
    if (t < nchunk) cntB[b * nchunk + t] = s[t] - v;
    if (t == 511) tot[b] = s[511];
}

// ---------------- exclusive scan over buckets -> bucket bases ----------------
__global__ __launch_bounds__(512) void base_kernel(
    const int* __restrict__ tot_d, const int* __restrict__ tot_s,
    int* __restrict__ base_d, int* __restrict__ base_s, int nbuck) {
    __shared__ int s[512];
    int t = threadIdx.x;
    for (int which = 0; which < 2; ++which) {
        const int* tot = which ? tot_s : tot_d;
        int* base = which ? base_s : base_d;
        int v = (t < nbuck) ? tot[t] : 0;
        s[t] = v;
        __syncthreads();
        for (int d = 1; d < 512; d <<= 1) {
            int u = (t >= d) ? s[t - d] : 0;
            __syncthreads();
            s[t] += u;
            __syncthreads();
        }
        if (t < nbuck) base[t] = s[t] - v;
        if (t == nbuck - 1) base[nbuck] = s[t];
        __syncthreads();
    }
}

// ---------------- bin edges by dst-bucket (packed) and src-bucket (byte) ----------------
__global__ __launch_bounds__(256) void binpack_kernel(
    const int* __restrict__ es, const int* __restrict__ ed,
    const int* __restrict__ base_d, const int* __restrict__ base_s,
    const int* __restrict__ cntB_d, const int* __restrict__ cntB_s,
    int* __restrict__ bp_dst, unsigned char* __restrict__ bp_src,
    int E, int nchunk, int nbuck) {
    __shared__ int ld[512];
    __shared__ int ls[512];
    int t = threadIdx.x;
    int c = blockIdx.x;
    for (int i = t; i < nbuck; i += 256) {
        ld[i] = base_d[i] + cntB_d[i * nchunk + c];
        ls[i] = base_s[i] + cntB_s[i * nchunk + c];
    }
    __syncthreads();
    int base = c * ECHUNK;
    for (int i = t * 4; i < ECHUNK; i += 1024) {   // int4 loads; E%4==0
        int e = base + i;
        if (e < E) {
            int4 s4 = *(const int4*)(es + e);
            int4 d4 = *(const int4*)(ed + e);
            int pd, ps;
            pd = atomicAdd(&ld[d4.x >> 8], 1); bp_dst[pd] = s4.x | ((d4.x & 255) << 24);
            pd = atomicAdd(&ld[d4.y >> 8], 1); bp_dst[pd] = s4.y | ((d4.y & 255) << 24);
            pd = atomicAdd(&ld[d4.z >> 8], 1); bp_dst[pd] = s4.z | ((d4.z & 255) << 24);
            pd = atomicAdd(&ld[d4.w >> 8], 1); bp_dst[pd] = s4.w | ((d4.w & 255) << 24);
            ps = atomicAdd(&ls[s4.x >> 8], 1); bp_src[ps] = (unsigned char)(s4.x & 255);
            ps = atomicAdd(&ls[s4.y >> 8], 1); bp_src[ps] = (unsigned char)(s4.y & 255);
            ps = atomicAdd(&ls[s4.z >> 8], 1); bp_src[ps] = (unsigned char)(s4.z & 255);
            ps = atomicAdd(&ls[s4.w >> 8], 1); bp_src[ps] = (unsigned char)(s4.w & 255);
        }
    }
}

// ---------------- per-bucket src counts -> dense out-degree write ----------------
__global__ __launch_bounds__(256) void srccount_kernel(
    const unsigned char* __restrict__ bp_src, const int* __restrict__ base_s,
    int* __restrict__ ds, int n) {
    __shared__ int cnt[256];
    int t = threadIdx.x;
    int b = blockIdx.x;
    cnt[t] = 0;
    __syncthreads();
    int lo = base_s[b], hi = base_s[b + 1];
    for (int i = lo + t; i < hi; i += 256) atomicAdd(&cnt[bp_src[i]], 1);
    __syncthreads();
    int node = (b << 8) + t;
    if (node < n) ds[node] = cnt[t];
}

// ---------------- per-bucket dst counts -> off[] + csr fill (dense region) ----------------
__global__ __launch_bounds__(256) void dstfill_kernel(
    const int* __restrict__ bp_dst, const int* __restrict__ base_d,
    int* __restrict__ off, int* __restrict__ csr, int n, int E) {
    __shared__ int cnt[256];
    __shared__ int s[256];
    __shared__ int cur[256];
    int t = threadIdx.x;
    int b = blockIdx.x;
    cnt[t] = 0;
    __syncthreads();
    int lo = base_d[b], hi = base_d[b + 1];
    for (int i = lo + t; i < hi; i += 256)
        atomicAdd(&cnt[(int)((unsigned)bp_dst[i] >> 24)], 1);
    __syncthreads();
    int v = cnt[t];
    s[t] = v;
    __syncthreads();
    for (int d = 1; d < 256; d <<= 1) {
        int u = (t >= d) ? s[t - d] : 0;
        __syncthreads();
        s[t] += u;
        __syncthreads();
    }
    int obase = lo + s[t] - v;
    int node = (b << 8) + t;
    if (node < n) off[node] = obase;
    cur[t] = obase;
    if (b == 0 && t == 0) off[n] = E;
    __syncthreads();
    for (int i = lo + t; i < hi; i += 256) {
        int w = bp_dst[i];
        int src = w & 0xFFFFFF;
        int d = (int)((unsigned)w >> 24);
        int slot = atomicAdd(&cur[d], 1);
        csr[slot] = src;
    }
}

// ---------------- x = bf16( (h * rsqrt(out_deg)) @ W ) ----------------
__global__ __launch_bounds__(256) void gemm_kernel(const float* __restrict__ h,
                                                   const float* __restrict__ W,
                                                   const int* __restrict__ ds,
                                                   unsigned short* __restrict__ x, int n) {
    __shared__ float Ws[IN_DIM * OUT_DIM];   // 32 KB
    __shared__ float hs[64][68];             // 17.4 KB
    int tid = threadIdx.x;
    int row0 = blockIdx.x * 64;

    {
        const float4* W4 = (const float4*)W;
        float4* Ws4 = (float4*)Ws;
        for (int i = tid; i < IN_DIM * OUT_DIM / 4; i += 256) Ws4[i] = W4[i];
    }

    int tc = tid & 15, tr = tid >> 4;
    int r0 = tr * 4, c0 = tc * 4;
    float acc[4][4];
#pragma unroll
    for (int i = 0; i < 4; i++)
#pragma unroll
        for (int j = 0; j < 4; j++) acc[i][j] = 0.f;

    for (int kh = 0; kh < 2; ++kh) {
        __syncthreads();
        for (int i = tid; i < 1024; i += 256) {
            int r = i >> 4, kq = i & 15;
            int row = row0 + r;
            float4 v = make_float4(0.f, 0.f, 0.f, 0.f);
            if (row < n) {
                v = ((const float4*)(h + (size_t)row * IN_DIM + kh * 64))[kq];
                float s = rsqrtf((float)max(ds[row], 1));
                v.x *= s; v.y *= s; v.z *= s; v.w *= s;
            }
            *(float4*)&hs[r][kq * 4] = v;
        }
        __syncthreads();
#pragma unroll
        for (int k = 0; k < 64; k += 4) {
            float4 a[4], w[4];
#pragma unroll
            for (int i = 0; i < 4; i++) a[i] = *(const float4*)&hs[r0 + i][k];
            int kg = (kh * 64 + k) * OUT_DIM + c0;
#pragma unroll
            for (int q = 0; q < 4; q++) w[q] = *(const float4*)&Ws[kg + q * OUT_DIM];
#pragma unroll
            for (int q = 0; q < 4; q++) {
#pragma unroll
                for (int i = 0; i < 4; i++) {
                    float aiq = (q == 0) ? a[i].x : (q == 1) ? a[i].y : (q == 2) ? a[i].z : a[i].w;
                    acc[i][0] += aiq * w[q].x;
                    acc[i][1] += aiq * w[q].y;
                    acc[i][2] += aiq * w[q].z;
                    acc[i][3] += aiq * w[q].w;
                }
            }
        }
    }
#pragma unroll
    for (int i = 0; i < 4; i++) {
        int row = row0 + r0 + i;
        if (row < n) {
            unsigned p0 = (unsigned)f2b(acc[i][0]) | ((unsigned)f2b(acc[i][1]) << 16);
            unsigned p1 = (unsigned)f2b(acc[i][2]) | ((unsigned)f2b(acc[i][3]) << 16);
            uint2 pk = make_uint2(p0, p1);
            *(uint2*)&x[(size_t)row * OUT_DIM + c0] = pk;
        }
    }
}

// ---------------- gather-sum per dst node (bf16 x) + fused epilogue ----------------
// 8 lanes x 16B (8 bf16) per node -> 8 nodes per wave, 32 nodes per block.
__global__ __launch_bounds__(256) void gather_kernel(const unsigned short* __restrict__ x,
                                                     const int* __restrict__ csr,
                                                     const int* __restrict__ off,
                                                     const float* __restrict__ b,
                                                     float* __restrict__ out, int n) {
    int g = threadIdx.x >> 3;       // node slot in block (0..31)
    int p = threadIdx.x & 7;        // 8-bf16 column group
    int v = blockIdx.x * 32 + g;
    if (v >= n) return;
    int s0 = off[v], s1 = off[v + 1];
    float a0 = 0.f, a1 = 0.f, a2 = 0.f, a3 = 0.f, a4 = 0.f, a5 = 0.f, a6 = 0.f, a7 = 0.f;
    int j = s0;
    for (; j + 2 <= s1; j += 2) {
        int n0 = csr[j], n1 = csr[j + 1];
        uint4 w0 = ((const uint4*)(x + (size_t)n0 * OUT_DIM))[p];
        uint4 w1 = ((const uint4*)(x + (size_t)n1 * OUT_DIM))[p];
        a0 += bf_lo(w0.x) + bf_lo(w1.x);
        a1 += bf_hi(w0.x) + bf_hi(w1.x);
        a2 += bf_lo(w0.y) + bf_lo(w1.y);
        a3 += bf_hi(w0.y) + bf_hi(w1.y);
        a4 += bf_lo(w0.z) + bf_lo(w1.z);
        a5 += bf_hi(w0.z) + bf_hi(w1.z);
        a6 += bf_lo(w0.w) + bf_lo(w1.w);
        a7 += bf_hi(w0.w) + bf_hi(w1.w);
    }
    if (j < s1) {
        uint4 w0 = ((const uint4*)(x + (size_t)csr[j] * OUT_DIM))[p];
        a0 += bf_lo(w0.x); a1 += bf_hi(w0.x);
        a2 += bf_lo(w0.y); a3 += bf_hi(w0.y);
        a4 += bf_lo(w0.z); a5 += bf_hi(w0.z);
        a6 += bf_lo(w0.w); a7 += bf_hi(w0.w);
    }
    float nd = rsqrtf((float)max(s1 - s0, 1));
    float4 b0 = ((const float4*)b)[p * 2];
    float4 b1 = ((const float4*)b)[p * 2 + 1];
    float4 r0, r1;
    r0.x = a0 * nd + b0.x; r0.y = a1 * nd + b0.y;
    r0.z = a2 * nd + b0.z; r0.w = a3 * nd + b0.w;
    r1.x = a4 * nd + b1.x; r1.y = a5 * nd + b1.y;
    r1.z = a6 * nd + b1.z; r1.w = a7 * nd + b1.w;
    r0.x = (r0.x >= 0.f) ? r0.x : NEG_SLOPE * r0.x;
    r0.y = (r0.y >= 0.f) ? r0.y : NEG_SLOPE * r0.y;
    r0.z = (r0.z >= 0.f) ? r0.z : NEG_SLOPE * r0.z;
    r0.w = (r0.w >= 0.f) ? r0.w : NEG_SLOPE * r0.w;
    r1.x = (r1.x >= 0.f) ? r1.x : NEG_SLOPE * r1.x;
    r1.y = (r1.y >= 0.f) ? r1.y : NEG_SLOPE * r1.y;
    r1.z = (r1.z >= 0.f) ? r1.z : NEG_SLOPE * r1.z;
    r1.w = (r1.w >= 0.f) ? r1.w : NEG_SLOPE * r1.w;
    float* orow = out + (size_t)v * OUT_DIM + p * 8;
    *(float4*)orow = r0;
    *(float4*)(orow + 4) = r1;
}

extern "C" void kernel_launch(void* const* d_in, const int* in_sizes, int n_in,
                              void* d_out, int out_size, void* d_ws, size_t ws_size,
                              hipStream_t stream) {
    const float* h = (const float*)d_in[0];
    const float* W = (const float*)d_in[1];
    const float* b = (const float*)d_in[2];
    const int* esrc = (const int*)d_in[3];
    const int* edst = (const int*)d_in[4];
    int n = in_sizes[0] / IN_DIM;   // 100000
    int E = in_sizes[3];            // 1600000
    float* out = (float*)d_out;

    // ws layout: ds[n] | off[n+4] | csr[E] | x[n*64 bf16]
    char* ws = (char*)d_ws;
    int* ds  = (int*)ws;
    int* off = (int*)(ws + (size_t)n * 4);
    int* csr = (int*)(ws + (size_t)n * 8 + 16);
    unsigned short* x = (unsigned short*)(ws + (size_t)n * 8 + 16 + (size_t)E * 4);

    int nchunk = (E + ECHUNK - 1) / ECHUNK;   // 391
    int nbuck  = (n + 255) >> 8;              // 391

    // transients aliased into x's 12.8 MB (all consumed before gemm writes x):
    char* xb = (char*)x;
    int* bp_dst = (int*)xb;                                   // 6.4 MB
    unsigned char* bp_src = (unsigned char*)(xb + 6600000);   // 1.6 MB
    int* cntA_d = (int*)(xb + 8400000);                       // 611 KB
    int* cntA_s = (int*)(xb + 9100000);
    int* cntB_d = (int*)(xb + 9800000);
    int* cntB_s = (int*)(xb + 10500000);
    int* tot_d  = (int*)(xb + 11200000);                      // nbuck+1
    int* tot_s  = (int*)(xb + 11210000);
    int* base_d = (int*)(xb + 11220000);                      // nbuck+1
    int* base_s = (int*)(xb + 11230000);

    hist_kernel<<<nchunk, 256, 0, stream>>>(esrc, edst, cntA_d, cntA_s, E, nbuck);
    cntscan_kernel<<<2 * nbuck, 512, 0, stream>>>(cntA_d, cntA_s, cntB_d, cntB_s,
                                                  tot_d, tot_s, nchunk, nbuck);
    base_kernel<<<1, 512, 0, stream>>>(tot_d, tot_s, base_d, base_s, nbuck);
    binpack_kernel<<<nchunk, 256, 0, stream>>>(esrc, edst, base_d, base_s,
                                               cntB_d, cntB_s, bp_dst, bp_src,
                                               E, nchunk, nbuck);
    srccount_kernel<<<nbuck, 256, 0, stream>>>(bp_src, base_s, ds, n);
    dstfill_kernel<<<nbuck, 256, 0, stream>>>(bp_dst, base_d, off, csr, n, E);
    gemm_kernel<<<(n + 63) / 64, 256, 0, stream>>>(h, W, ds, x, n);
    gather_kernel<<<(n + 31) / 32, 256, 0, stream>>>(x, csr, off, b, out, n);
}

// Round 7
// 134.110 us; speedup vs baseline: 11.4808x; 1.1268x over previous
//
#include <hip/hip_runtime.h>

#define IN_DIM 128
#define OUT_DIM 64
#define NEG_SLOPE 0.01f
#define ECHUNK 4096       // edges per binning block
// bucket = node >> 8  (256 nodes per bucket)

typedef __attribute__((ext_vector_type(8))) short short8;
typedef __attribute__((ext_vector_type(4))) float floatx4;

// bf16 helpers: memory layout = 16-bit, value = bits<<16
__device__ inline float bf_lo(unsigned u) { union { unsigned i; float f; } c; c.i = u << 16; return c.f; }
__device__ inline float bf_hi(unsigned u) { union { unsigned i; float f; } c; c.i = u & 0xFFFF0000u; return c.f; }
__device__ inline unsigned short f2b(float f) {
    union { float f; unsigned i; } c; c.f = f;
    unsigned u = c.i + 0x7FFFu + ((c.i >> 16) & 1u);   // round-to-nearest-even
    return (unsigned short)(u >> 16);
}

// ---------------- per-chunk bucket histograms (dst and src), LDS only ----------------
__global__ __launch_bounds__(256) void hist_kernel(
    const int* __restrict__ es, const int* __restrict__ ed,
    int* __restrict__ cntA_d, int* __restrict__ cntA_s, int E, int nbuck) {
    __shared__ int hd[512];
    __shared__ int hs[512];
    int t = threadIdx.x;
    for (int i = t; i < nbuck; i += 256) { hd[i] = 0; hs[i] = 0; }
    __syncthreads();
    int base = blockIdx.x * ECHUNK;
    for (int i = t * 4; i < ECHUNK; i += 1024) {   // int4 loads; E%4==0
        int e = base + i;
        if (e < E) {
            int4 d4 = *(const int4*)(ed + e);
            int4 s4 = *(const int4*)(es + e);
            atomicAdd(&hd[d4.x >> 8], 1); atomicAdd(&hd[d4.y >> 8], 1);
            atomicAdd(&hd[d4.z >> 8], 1); atomicAdd(&hd[d4.w >> 8], 1);
            atomicAdd(&hs[s4.x >> 8], 1); atomicAdd(&hs[s4.y >> 8], 1);
            atomicAdd(&hs[s4.z >> 8], 1); atomicAdd(&hs[s4.w >> 8], 1);
        }
    }
    __syncthreads();
    int row = blockIdx.x * nbuck;
    for (int i = t; i < nbuck; i += 256) {
        cntA_d[row + i] = hd[i];
        cntA_s[row + i] = hs[i];
    }
}

// ---------------- per-bucket exclusive scan over chunks + bucket totals ----------------
__global__ __launch_bounds__(512) void cntscan_kernel(
    const int* __restrict__ cntA_d, const int* __restrict__ cntA_s,
    int* __restrict__ cntB_d, int* __restrict__ cntB_s,
    int* __restrict__ tot_d, int* __restrict__ tot_s,
    int nchunk, int nbuck) {
    __shared__ int s[512];
    int t = threadIdx.x;
    int bid = blockIdx.x;
    const int* cntA = (bid < nbuck) ? cntA_d : cntA_s;
    int* cntB = (bid < nbuck) ? cntB_d : cntB_s;
    int* tot = (bid < nbuck) ? tot_d : tot_s;
    int b = (bid < nbuck) ? bid : bid - nbuck;
    int v = (t < nchunk) ? cntA[t * nbuck + b] : 0;
    s[t] = v;
    __syncthreads();
    for (int d = 1; d < 512; d <<= 1) {
        int u = (t >= d) ? s[t - d] : 0;
        __syncthreads();
        s[t] += u;
        __syncthreads();
    }
    if (t < nchunk) cntB[b * nchunk + t] = s[t] - v;
    if (t == 511) tot[b] = s[511];
}

// ---------------- exclusive scan over buckets -> bucket bases ----------------
__global__ __launch_bounds__(512) void base_kernel(
    const int* __restrict__ tot_d, const int* __restrict__ tot_s,
    int* __restrict__ base_d, int* __restrict__ base_s, int nbuck) {
    __shared__ int s[512];
    int t = threadIdx.x;
    for (int which = 0; which < 2; ++which) {
        const int* tot = which ? tot_s : tot_d;
        int* base = which ? base_s : base_d;
        int v = (t < nbuck) ? tot[t] : 0;
        s[t] = v;
        __syncthreads();
        for (int d = 1; d < 512; d <<= 1) {
            int u = (t >= d) ? s[t - d] : 0;
            __syncthreads();
            s[t] += u;
            __syncthreads();
        }
        if (t < nbuck) base[t] = s[t] - v;
        if (t == nbuck - 1) base[nbuck] = s[t];
        __syncthreads();
    }
}

// ---------------- bin edges by dst-bucket (packed) and src-bucket (byte) ----------------
__global__ __launch_bounds__(256) void binpack_kernel(
    const int* __restrict__ es, const int* __restrict__ ed,
    const int* __restrict__ base_d, const int* __restrict__ base_s,
    const int* __restrict__ cntB_d, const int* __restrict__ cntB_s,
    int* __restrict__ bp_dst, unsigned char* __restrict__ bp_src,
    int E, int nchunk, int nbuck) {
    __shared__ int ld[512];
    __shared__ int ls[512];
    int t = threadIdx.x;
    int c = blockIdx.x;
    for (int i = t; i < nbuck; i += 256) {
        ld[i] = base_d[i] + cntB_d[i * nchunk + c];
        ls[i] = base_s[i] + cntB_s[i * nchunk + c];
    }
    __syncthreads();
    int base = c * ECHUNK;
    for (int i = t * 4; i < ECHUNK; i += 1024) {   // int4 loads; E%4==0
        int e = base + i;
        if (e < E) {
            int4 s4 = *(const int4*)(es + e);
            int4 d4 = *(const int4*)(ed + e);
            int pd, ps;
            pd = atomicAdd(&ld[d4.x >> 8], 1); bp_dst[pd] = s4.x | ((d4.x & 255) << 24);
            pd = atomicAdd(&ld[d4.y >> 8], 1); bp_dst[pd] = s4.y | ((d4.y & 255) << 24);
            pd = atomicAdd(&ld[d4.z >> 8], 1); bp_dst[pd] = s4.z | ((d4.z & 255) << 24);
            pd = atomicAdd(&ld[d4.w >> 8], 1); bp_dst[pd] = s4.w | ((d4.w & 255) << 24);
            ps = atomicAdd(&ls[s4.x >> 8], 1); bp_src[ps] = (unsigned char)(s4.x & 255);
            ps = atomicAdd(&ls[s4.y >> 8], 1); bp_src[ps] = (unsigned char)(s4.y & 255);
            ps = atomicAdd(&ls[s4.z >> 8], 1); bp_src[ps] = (unsigned char)(s4.z & 255);
            ps = atomicAdd(&ls[s4.w >> 8], 1); bp_src[ps] = (unsigned char)(s4.w & 255);
        }
    }
}

// ---------------- per-bucket src counts -> dense out-degree write ----------------
__global__ __launch_bounds__(256) void srccount_kernel(
    const unsigned char* __restrict__ bp_src, const int* __restrict__ base_s,
    int* __restrict__ ds, int n) {
    __shared__ int cnt[256];
    int t = threadIdx.x;
    int b = blockIdx.x;
    cnt[t] = 0;
    __syncthreads();
    int lo = base_s[b], hi = base_s[b + 1];
    for (int i = lo + t; i < hi; i += 256) atomicAdd(&cnt[bp_src[i]], 1);
    __syncthreads();
    int node = (b << 8) + t;
    if (node < n) ds[node] = cnt[t];
}

// ---------------- per-bucket dst counts -> off[] + csr fill (dense region) ----------------
__global__ __launch_bounds__(256) void dstfill_kernel(
    const int* __restrict__ bp_dst, const int* __restrict__ base_d,
    int* __restrict__ off, int* __restrict__ csr, int n, int E) {
    __shared__ int cnt[256];
    __shared__ int s[256];
    __shared__ int cur[256];
    int t = threadIdx.x;
    int b = blockIdx.x;
    cnt[t] = 0;
    __syncthreads();
    int lo = base_d[b], hi = base_d[b + 1];
    for (int i = lo + t; i < hi; i += 256)
        atomicAdd(&cnt[(int)((unsigned)bp_dst[i] >> 24)], 1);
    __syncthreads();
    int v = cnt[t];
    s[t] = v;
    __syncthreads();
    for (int d = 1; d < 256; d <<= 1) {
        int u = (t >= d) ? s[t - d] : 0;
        __syncthreads();
        s[t] += u;
        __syncthreads();
    }
    int obase = lo + s[t] - v;
    int node = (b << 8) + t;
    if (node < n) off[node] = obase;
    cur[t] = obase;
    if (b == 0 && t == 0) off[n] = E;
    __syncthreads();
    for (int i = lo + t; i < hi; i += 256) {
        int w = bp_dst[i];
        int src = w & 0xFFFFFF;
        int d = (int)((unsigned)w >> 24);
        int slot = atomicAdd(&cur[d], 1);
        csr[slot] = src;
    }
}

// ---------------- x = bf16( rsqrt(out_deg) * (H @ W) ) via MFMA ----------------
// 64 rows/block, 4 waves, each wave 16 rows x 64 cols. A-frags straight from
// global (bf16 cast in-reg); W^T staged once in LDS (pad 136 -> 2-way banks = free).
__global__ __launch_bounds__(256) void gemm_kernel(const float* __restrict__ h,
                                                   const float* __restrict__ W,
                                                   const int* __restrict__ ds,
                                                   unsigned short* __restrict__ x, int n) {
    __shared__ unsigned short Wt[OUT_DIM][136];   // [col][k], 17.4 KB
    int tid = threadIdx.x;

    {   // stage W^T as bf16: W is [128][64] row-major
        const float4* W4 = (const float4*)W;
        for (int i = tid; i < IN_DIM * OUT_DIM / 4; i += 256) {
            float4 v = W4[i];
            int k = i >> 4, c = (i & 15) * 4;
            Wt[c + 0][k] = f2b(v.x);
            Wt[c + 1][k] = f2b(v.y);
            Wt[c + 2][k] = f2b(v.z);
            Wt[c + 3][k] = f2b(v.w);
        }
    }
    __syncthreads();

    int wid = tid >> 6, lane = tid & 63;
    int rbase = blockIdx.x * 64 + wid * 16;
    int row = rbase + (lane & 15);
    int kg = lane >> 4;                       // 0..3
    int rowc = min(row, n - 1);

    // load full A row-slice: 4 K-steps x 8 floats per lane
    const float* hrow = h + (size_t)rowc * IN_DIM + kg * 8;
    float4 af[8];
#pragma unroll
    for (int ks = 0; ks < 4; ks++) {
        af[2 * ks]     = *(const float4*)(hrow + ks * 32);
        af[2 * ks + 1] = *(const float4*)(hrow + ks * 32 + 4);
    }
    short8 afr[4];
#pragma unroll
    for (int ks = 0; ks < 4; ks++) {
        afr[ks][0] = (short)f2b(af[2 * ks].x);
        afr[ks][1] = (short)f2b(af[2 * ks].y);
        afr[ks][2] = (short)f2b(af[2 * ks].z);
        afr[ks][3] = (short)f2b(af[2 * ks].w);
        afr[ks][4] = (short)f2b(af[2 * ks + 1].x);
        afr[ks][5] = (short)f2b(af[2 * ks + 1].y);
        afr[ks][6] = (short)f2b(af[2 * ks + 1].z);
        afr[ks][7] = (short)f2b(af[2 * ks + 1].w);
    }

    floatx4 acc[4];
#pragma unroll
    for (int gf = 0; gf < 4; gf++) acc[gf] = (floatx4){0.f, 0.f, 0.f, 0.f};

#pragma unroll
    for (int ks = 0; ks < 4; ks++) {
#pragma unroll
        for (int gf = 0; gf < 4; gf++) {
            int col = gf * 16 + (lane & 15);
            short8 bfr = *(const short8*)&Wt[col][ks * 32 + kg * 8];
            acc[gf] = __builtin_amdgcn_mfma_f32_16x16x32_bf16(afr[ks], bfr, acc[gf], 0, 0, 0);
        }
    }

    // C/D layout: col = lane&15 (within gf*16), row = (lane>>4)*4 + reg
#pragma unroll
    for (int r = 0; r < 4; r++) {
        int orow = rbase + (lane >> 4) * 4 + r;
        if (orow < n) {
            float sc = rsqrtf((float)max(ds[orow], 1));
            unsigned short* xr = x + (size_t)orow * OUT_DIM + (lane & 15);
#pragma unroll
            for (int gf = 0; gf < 4; gf++)
                xr[gf * 16] = f2b(acc[gf][r] * sc);
        }
    }
}

// ---------------- gather-sum per dst node (bf16 x) + fused epilogue ----------------
// 8 lanes x 16B (8 bf16) per node; unroll-4 for memory-level parallelism.
__global__ __launch_bounds__(256) void gather_kernel(const unsigned short* __restrict__ x,
                                                     const int* __restrict__ csr,
                                                     const int* __restrict__ off,
                                                     const float* __restrict__ b,
                                                     float* __restrict__ out, int n) {
    int g = threadIdx.x >> 3;       // node slot in block (0..31)
    int p = threadIdx.x & 7;        // 8-bf16 column group
    int v = blockIdx.x * 32 + g;
    if (v >= n) return;
    int s0 = off[v], s1 = off[v + 1];
    float a0 = 0.f, a1 = 0.f, a2 = 0.f, a3 = 0.f, a4 = 0.f, a5 = 0.f, a6 = 0.f, a7 = 0.f;
    int j = s0;
    for (; j + 4 <= s1; j += 4) {
        int n0 = csr[j], n1 = csr[j + 1], n2 = csr[j + 2], n3 = csr[j + 3];
        uint4 w0 = ((const uint4*)(x + (size_t)n0 * OUT_DIM))[p];
        uint4 w1 = ((const uint4*)(x + (size_t)n1 * OUT_DIM))[p];
        uint4 w2 = ((const uint4*)(x + (size_t)n2 * OUT_DIM))[p];
        uint4 w3 = ((const uint4*)(x + (size_t)n3 * OUT_DIM))[p];
        a0 += (bf_lo(w0.x) + bf_lo(w1.x)) + (bf_lo(w2.x) + bf_lo(w3.x));
        a1 += (bf_hi(w0.x) + bf_hi(w1.x)) + (bf_hi(w2.x) + bf_hi(w3.x));
        a2 += (bf_lo(w0.y) + bf_lo(w1.y)) + (bf_lo(w2.y) + bf_lo(w3.y));
        a3 += (bf_hi(w0.y) + bf_hi(w1.y)) + (bf_hi(w2.y) + bf_hi(w3.y));
        a4 += (bf_lo(w0.z) + bf_lo(w1.z)) + (bf_lo(w2.z) + bf_lo(w3.z));
        a5 += (bf_hi(w0.z) + bf_hi(w1.z)) + (bf_hi(w2.z) + bf_hi(w3.z));
        a6 += (bf_lo(w0.w) + bf_lo(w1.w)) + (bf_lo(w2.w) + bf_lo(w3.w));
        a7 += (bf_hi(w0.w) + bf_hi(w1.w)) + (bf_hi(w2.w) + bf_hi(w3.w));
    }
    for (; j < s1; j++) {
        uint4 w0 = ((const uint4*)(x + (size_t)csr[j] * OUT_DIM))[p];
        a0 += bf_lo(w0.x); a1 += bf_hi(w0.x);
        a2 += bf_lo(w0.y); a3 += bf_hi(w0.y);
        a4 += bf_lo(w0.z); a5 += bf_hi(w0.z);
        a6 += bf_lo(w0.w); a7 += bf_hi(w0.w);
    }
    float nd = rsqrtf((float)max(s1 - s0, 1));
    float4 b0 = ((const float4*)b)[p * 2];
    float4 b1 = ((const float4*)b)[p * 2 + 1];
    float4 r0, r1;
    r0.x = a0 * nd + b0.x; r0.y = a1 * nd + b0.y;
    r0.z = a2 * nd + b0.z; r0.w = a3 * nd + b0.w;
    r1.x = a4 * nd + b1.x; r1.y = a5 * nd + b1.y;
    r1.z = a6 * nd + b1.z; r1.w = a7 * nd + b1.w;
    r0.x = (r0.x >= 0.f) ? r0.x : NEG_SLOPE * r0.x;
    r0.y = (r0.y >= 0.f) ? r0.y : NEG_SLOPE * r0.y;
    r0.z = (r0.z >= 0.f) ? r0.z : NEG_SLOPE * r0.z;
    r0.w = (r0.w >= 0.f) ? r0.w : NEG_SLOPE * r0.w;
    r1.x = (r1.x >= 0.f) ? r1.x : NEG_SLOPE * r1.x;
    r1.y = (r1.y >= 0.f) ? r1.y : NEG_SLOPE * r1.y;
    r1.z = (r1.z >= 0.f) ? r1.z : NEG_SLOPE * r1.z;
    r1.w = (r1.w >= 0.f) ? r1.w : NEG_SLOPE * r1.w;
    float* orow = out + (size_t)v * OUT_DIM + p * 8;
    *(float4*)orow = r0;
    *(float4*)(orow + 4) = r1;
}

extern "C" void kernel_launch(void* const* d_in, const int* in_sizes, int n_in,
                              void* d_out, int out_size, void* d_ws, size_t ws_size,
                              hipStream_t stream) {
    const float* h = (const float*)d_in[0];
    const float* W = (const float*)d_in[1];
    const float* b = (const float*)d_in[2];
    const int* esrc = (const int*)d_in[3];
    const int* edst = (const int*)d_in[4];
    int n = in_sizes[0] / IN_DIM;   // 100000
    int E = in_sizes[3];            // 1600000
    float* out = (float*)d_out;

    // ws layout: ds[n] | off[n+4] | csr[E] | x[n*64 bf16]
    char* ws = (char*)d_ws;
    int* ds  = (int*)ws;
    int* off = (int*)(ws + (size_t)n * 4);
    int* csr = (int*)(ws + (size_t)n * 8 + 16);
    unsigned short* x = (unsigned short*)(ws + (size_t)n * 8 + 16 + (size_t)E * 4);

    int nchunk = (E + ECHUNK - 1) / ECHUNK;   // 391
    int nbuck  = (n + 255) >> 8;              // 391

    // transients aliased into x's 12.8 MB (all consumed before gemm writes x):
    char* xb = (char*)x;
    int* bp_dst = (int*)xb;                                   // 6.4 MB
    unsigned char* bp_src = (unsigned char*)(xb + 6600000);   // 1.6 MB
    int* cntA_d = (int*)(xb + 8400000);                       // 611 KB
    int* cntA_s = (int*)(xb + 9100000);
    int* cntB_d = (int*)(xb + 9800000);
    int* cntB_s = (int*)(xb + 10500000);
    int* tot_d  = (int*)(xb + 11200000);                      // nbuck+1
    int* tot_s  = (int*)(xb + 11210000);
    int* base_d = (int*)(xb + 11220000);                      // nbuck+1
    int* base_s = (int*)(xb + 11230000);

    hist_kernel<<<nchunk, 256, 0, stream>>>(esrc, edst, cntA_d, cntA_s, E, nbuck);
    cntscan_kernel<<<2 * nbuck, 512, 0, stream>>>(cntA_d, cntA_s, cntB_d, cntB_s,
                                                  tot_d, tot_s, nchunk, nbuck);
    base_kernel<<<1, 512, 0, stream>>>(tot_d, tot_s, base_d, base_s, nbuck);
    binpack_kernel<<<nchunk, 256, 0, stream>>>(esrc, edst, base_d, base_s,
                                               cntB_d, cntB_s, bp_dst, bp_src,
                                               E, nchunk, nbuck);
    srccount_kernel<<<nbuck, 256, 0, stream>>>(bp_src, base_s, ds, n);
    dstfill_kernel<<<nbuck, 256, 0, stream>>>(bp_dst, base_d, off, csr, n, E);
    gemm_kernel<<<(n + 63) / 64, 256, 0, stream>>>(h, W, ds, x, n);
    gather_kernel<<<(n + 31) / 32, 256, 0, stream>>>(x, csr, off, b, out, n);
}